// Round 10
// baseline (443.829 us; speedup 1.0000x reference)
//
#include <hip/hip_runtime.h>
#include <hip/hip_bf16.h>

// RNN: B=1024, T=512, H=128, +4 autoregressive steps -> out (1024, 516)
// Round 10: anti-phased dual recurrence.
//  R9 closing analysis: barrier phase-aligns all waves -> per-CU pipe demands
//  ADD (LDS 385 + MFMA 256 + VALU 270 + barrier ~ 960 cyc/step, measured 958).
//  Fix: 32 blocks x 512 thr; BM=32 = 2 independent 16-row groups. Waves 0-3 =
//  group A, 4-7 = group B (one of each per SIMD). Each step = M-phase (ds_read
//  h + MFMA -> persistent acc) + E-phase (tanh + h write), anti-phased: alpha
//  does M while beta does E, swap each interval -> MFMA pipe and VALU/trans
//  overlap instead of serializing. MTW=2 halves LDS duplication (4 reads/wave).
//  Single h buffer per group (read/write barrier-separated). Decoder via MFMA
//  dec tile (A: wv3/SIMD3, B: wv4/SIMD0); y -> pq one interval ahead of use.

#define BB 1024
#define TT 512
#define HH 128
#define TOUT 516
#define BM 16          // batch rows per group
#define G 2            // groups per block
#define MTW 2          // m-tiles per wave (4 waves/group * 2 * 16 = 128)
#define HSTR 136       // h stride in bf16 (272 B)
#define XSTR 513       // xs stride (dwords)
#define YSTR 517       // ybuf stride (dwords)

typedef __attribute__((ext_vector_type(8))) short bf16x8;
typedef __attribute__((ext_vector_type(4))) float f32x4;

#define MFMA_BF16 __builtin_amdgcn_mfma_f32_16x16x32_bf16

__device__ __forceinline__ short f2bs(float f) {
    __hip_bfloat16 h = __float2bfloat16(f);
    return __builtin_bit_cast(short, h);
}
__device__ __forceinline__ float bs2f(short s) {
    __hip_bfloat16 h = __builtin_bit_cast(__hip_bfloat16, s);
    return __bfloat162float(h);
}

__global__ void detect_dtype(const void* w, int* flag) {
    const int lane = threadIdx.x;  // 64 threads
    const __hip_bfloat16* p = (const __hip_bfloat16*)w;
    const float v0 = __bfloat162float(p[lane]);
    const float v1 = __bfloat162float(p[64 + lane]);
    const bool bad = !(fabsf(v0) < 100.0f) || !(fabsf(v1) < 100.0f);
    const unsigned long long m = __ballot(bad);
    if (lane == 0) *flag = (__popcll(m) > 4) ? 1 : 0;  // 1 => data is fp32
}

template <bool F32>
__device__ __forceinline__ float ldg(const void* p, int idx) {
    if (F32) return ((const float*)p)[idx];
    return __bfloat162float(((const __hip_bfloat16*)p)[idx]);
}

// pack 2 fp32 -> 1 dword of 2 bf16 (round-half-away; ties-only diff vs RNE)
__device__ __forceinline__ unsigned pkbf(float lo, float hi) {
    const unsigned ulo = __builtin_bit_cast(unsigned, lo) + 0x8000u;
    const unsigned uhi = __builtin_bit_cast(unsigned, hi) + 0x8000u;
    return __builtin_amdgcn_perm(uhi, ulo, 0x07060302u);  // {uhi[31:16], ulo[31:16]}
}

// M-phase: read h(T_-1), MFMA -> persistent acc; dec wave computes
// y(T_-1) = dec.h(T_-1)+db -> pq (and ybuf for T_>=1).
#define M_PHASE(T_) do {                                                        \
    bf16x8 bfrag[4];                                                            \
    _Pragma("unroll")                                                           \
    for (int kf = 0; kf < 4; ++kf)                                              \
        bfrag[kf] = *(const bf16x8*)&hbuf[g][n][kf * 32 + q * 8];               \
    _Pragma("unroll")                                                           \
    for (int m2 = 0; m2 < MTW; ++m2) {                                          \
        acc[m2][0] = (f32x4){0.f, 0.f, 0.f, 0.f};                               \
        acc[m2][1] = (f32x4){0.f, 0.f, 0.f, 0.f};                               \
    }                                                                           \
    _Pragma("unroll")                                                           \
    for (int kf = 0; kf < 4; ++kf) {                                            \
        const int hf = kf >> 1;                                                 \
        _Pragma("unroll")                                                       \
        for (int m2 = 0; m2 < MTW; ++m2) {                                      \
            acc[m2][hf] = MFMA_BF16(wa_hi[m2][kf], bfrag[kf], acc[m2][hf], 0, 0, 0); \
            if (F32)                                                            \
                acc[m2][hf] = MFMA_BF16(wa_lo[m2][kf], bfrag[kf], acc[m2][hf], 0, 0, 0); \
        }                                                                       \
    }                                                                           \
    if (isdec) {                                                                \
        f32x4 aD0 = (f32x4){0.f, 0.f, 0.f, 0.f};                                \
        f32x4 aD1 = (f32x4){0.f, 0.f, 0.f, 0.f};                                \
        aD0 = MFMA_BF16(wa_dhi[0], bfrag[0], aD0, 0, 0, 0);                     \
        aD0 = MFMA_BF16(wa_dhi[1], bfrag[1], aD0, 0, 0, 0);                     \
        aD1 = MFMA_BF16(wa_dhi[2], bfrag[2], aD1, 0, 0, 0);                     \
        aD1 = MFMA_BF16(wa_dhi[3], bfrag[3], aD1, 0, 0, 0);                     \
        if (q == 0) {                                                           \
            const float yv = aD0[0] + aD1[0] + dbv;                             \
            pq[g][n] = yv;                                                      \
            if ((T_) >= 1) ybuf[g * BM + n][(T_) - 1] = yv;                     \
        }                                                                       \
    }                                                                           \
} while (0)

// E-phase: h(T_) = tanh(acc + x(T_)*w0 + b); write to hbuf; prefetch x(T_+1).
#define E_PHASE(T_) do {                                                        \
    float xv;                                                                   \
    if ((T_) < TT) xv = xpref;                                                  \
    else           xv = pq[g][n];                                               \
    _Pragma("unroll")                                                           \
    for (int m2 = 0; m2 < MTW; ++m2) {                                          \
        float hv[4];                                                            \
        _Pragma("unroll")                                                       \
        for (int r = 0; r < 4; ++r) {                                           \
            const float z = acc[m2][0][r] + acc[m2][1][r]                       \
                          + fmaf(xv, w0v[m2][r], bsum[m2][r]);                  \
            const float e = __expf(z + z);                                      \
            hv[r] = fmaf(-2.0f, __builtin_amdgcn_rcpf(e + 1.0f), 1.0f);         \
        }                                                                       \
        uint2 pk;                                                               \
        pk.x = pkbf(hv[0], hv[1]);                                              \
        pk.y = pkbf(hv[2], hv[3]);                                              \
        *(uint2*)&hbuf[g][n][(w4 * MTW + m2) * 16 + q * 4] = pk;                \
    }                                                                           \
    if ((T_) + 1 < TT) xpref = xs[g * BM + n][(T_) + 1];                        \
} while (0)

// final dec-only pass: y(515) = dec.h(515)+db
#define MDEC_PHASE() do {                                                       \
    if (isdec) {                                                                \
        bf16x8 bfrag[4];                                                        \
        _Pragma("unroll")                                                       \
        for (int kf = 0; kf < 4; ++kf)                                          \
            bfrag[kf] = *(const bf16x8*)&hbuf[g][n][kf * 32 + q * 8];           \
        f32x4 aD0 = (f32x4){0.f, 0.f, 0.f, 0.f};                                \
        f32x4 aD1 = (f32x4){0.f, 0.f, 0.f, 0.f};                                \
        aD0 = MFMA_BF16(wa_dhi[0], bfrag[0], aD0, 0, 0, 0);                     \
        aD0 = MFMA_BF16(wa_dhi[1], bfrag[1], aD0, 0, 0, 0);                     \
        aD1 = MFMA_BF16(wa_dhi[2], bfrag[2], aD1, 0, 0, 0);                     \
        aD1 = MFMA_BF16(wa_dhi[3], bfrag[3], aD1, 0, 0, 0);                     \
        if (q == 0) ybuf[g * BM + n][TOUT - 1] = aD0[0] + aD1[0] + dbv;         \
    }                                                                           \
} while (0)

template <bool F32>
__device__ void rnn_body(const void* __restrict__ xg, const void* __restrict__ h0,
                         const void* __restrict__ w0, const void* __restrict__ b0,
                         const void* __restrict__ W,  const void* __restrict__ bw,
                         const void* __restrict__ dw, const void* __restrict__ db,
                         void* __restrict__ out,
                         float (*xs)[XSTR], float (*ybuf)[YSTR],
                         __hip_bfloat16 (*hbuf)[BM][HSTR], float (*pq)[BM])
{
    const int tid  = threadIdx.x;
    const int lane = tid & 63;
    const int wv   = tid >> 6;        // 0..7
    const int g    = wv >> 2;         // group 0/1
    const int w4   = wv & 3;          // wave within group (m-tile base)
    const int q    = lane >> 4;       // 0..3
    const int n    = lane & 15;       // batch col within group
    const int row0 = blockIdx.x * (G * BM);
    const bool isdec = (wv == 3) || (wv == 4);  // dec_A on SIMD3, dec_B on SIMD0

    // stage x (fp32 in LDS)
    for (int idx = tid; idx < G * BM * TT; idx += 512) {
        const int rg = idx >> 9, t2 = idx & (TT - 1);
        xs[rg][t2] = ldg<F32>(xg, (row0 + rg) * TT + t2);
    }
    // stage h0 as bf16 (single buffer per group)
    for (int idx = tid; idx < G * BM * HH; idx += 512) {
        const int gg = idx >> 11, rr = (idx >> 7) & (BM - 1), ii = idx & (HH - 1);
        hbuf[gg][rr][ii] = __float2bfloat16(ldg<F32>(h0, (row0 + gg * BM + rr) * HH + ii));
    }

    // preload W fragments (A-operand: A[m=lane&15][k=q*8+j]), hi/lo split
    bf16x8 wa_hi[MTW][4], wa_lo[MTW][4];
    #pragma unroll
    for (int m2 = 0; m2 < MTW; ++m2) {
        const int ia = (w4 * MTW + m2) * 16 + n;           // W row (output unit)
        #pragma unroll
        for (int kf = 0; kf < 4; ++kf) {
            const int kb = kf * 32 + q * 8;
            bf16x8 hi, lo;
            #pragma unroll
            for (int j = 0; j < 8; ++j) {
                const float f = ldg<F32>(W, ia * HH + kb + j);
                const short hs = f2bs(f);
                hi[j] = hs;
                lo[j] = F32 ? f2bs(f - bs2f(hs)) : (short)0;
            }
            wa_hi[m2][kf] = hi;
            wa_lo[m2][kf] = lo;
        }
    }
    // dec tile (hi only): A row 0 = dec_w, rows 1..15 = 0
    bf16x8 wa_dhi[4] = {};
    if (isdec) {
        #pragma unroll
        for (int kf = 0; kf < 4; ++kf) {
            const int kb = kf * 32 + q * 8;
            bf16x8 hi = {};
            if (n == 0) {
                #pragma unroll
                for (int j = 0; j < 8; ++j) hi[j] = f2bs(ldg<F32>(dw, kb + j));
            }
            wa_dhi[kf] = hi;
        }
    }
    // epilogue constants (C-layout rows: i = (w4*MTW+m2)*16 + q*4 + r)
    float bsum[MTW][4], w0v[MTW][4];
    #pragma unroll
    for (int m2 = 0; m2 < MTW; ++m2)
        #pragma unroll
        for (int r = 0; r < 4; ++r) {
            const int ic = (w4 * MTW + m2) * 16 + q * 4 + r;
            bsum[m2][r] = ldg<F32>(b0, ic) + ldg<F32>(bw, ic);
            w0v[m2][r]  = ldg<F32>(w0, ic);
        }
    const float dbv = ldg<F32>(db, 0);

    __syncthreads();

    f32x4 acc[MTW][2];            // persistent across M->E phases
    float xpref = xs[g * BM + n][0];

    // I0: alpha M(0); beta idle
    if (g == 0) M_PHASE(0);
    __syncthreads();

    // steady: intervals I(2t+1) [alpha E(t) | beta M(t)],
    //         I(2t+2) [alpha M(t+1) | beta E(t)], t = 0..514
    #pragma unroll 1
    for (int t = 0; t < 515; ++t) {
        if (g == 0) E_PHASE(t); else M_PHASE(t);
        __syncthreads();
        if (g == 0) M_PHASE(t + 1); else E_PHASE(t);
        __syncthreads();
    }
    // I1031: alpha E(515) | beta M(515)
    if (g == 0) E_PHASE(515); else M_PHASE(515);
    __syncthreads();
    // I1032: alpha dec-only y(515) | beta E(515)
    if (g == 0) MDEC_PHASE(); else E_PHASE(515);
    __syncthreads();
    // I1033: beta dec-only y(515)
    if (g == 1) MDEC_PHASE();
    __syncthreads();

    // flush outputs (coalesced over t)
    for (int rg = 0; rg < G * BM; ++rg)
        for (int t2 = tid; t2 < TOUT; t2 += 512) {
            const int o = (row0 + rg) * TOUT + t2;
            const float y = ybuf[rg][t2];
            if (F32) ((float*)out)[o] = y;
            else     ((__hip_bfloat16*)out)[o] = __float2bfloat16(y);
        }
}

__global__ __launch_bounds__(512, 2)
void rnn_mfma(const void* __restrict__ xg, const void* __restrict__ h0,
              const void* __restrict__ w0, const void* __restrict__ b0,
              const void* __restrict__ W,  const void* __restrict__ bw,
              const void* __restrict__ dw, const void* __restrict__ db,
              void* __restrict__ out, const int* __restrict__ flag)
{
    __shared__ float xs[G * BM][XSTR];                       // 65.7 KB
    __shared__ float ybuf[G * BM][YSTR];                     // 66.2 KB
    __shared__ __align__(16) __hip_bfloat16 hbuf[G][BM][HSTR]; // 8.7 KB
    __shared__ __align__(16) float pq[G][BM];                // 0.13 KB

    const int f = *(volatile const int*)flag;  // block-uniform
    if (f) rnn_body<true >(xg, h0, w0, b0, W, bw, dw, db, out, xs, ybuf, hbuf, pq);
    else   rnn_body<false>(xg, h0, w0, b0, W, bw, dw, db, out, xs, ybuf, hbuf, pq);
}

extern "C" void kernel_launch(void* const* d_in, const int* in_sizes, int n_in,
                              void* d_out, int out_size, void* d_ws, size_t ws_size,
                              hipStream_t stream) {
    int* flag = (int*)d_ws;
    detect_dtype<<<1, 64, 0, stream>>>(d_in[4], flag);  // probe fc_w
    rnn_mfma<<<BB / (G * BM), 512, 0, stream>>>(d_in[0], d_in[1], d_in[2], d_in[3],
                                                d_in[4], d_in[5], d_in[6], d_in[7],
                                                d_out, flag);
}

// Round 11
// 222.715 us; speedup vs baseline: 1.9928x; 1.9928x over previous
//
#include <hip/hip_runtime.h>
#include <hip/hip_bf16.h>

// RNN: B=1024, T=512, H=128, +4 autoregressive steps -> out (1024, 516)
// Round 11: R9 topology (64 blk x 8 waves, BM=16, 1 barrier/step) with:
//  - fp16 pipeline (W, h, dec): 10 mantissa bits -> no hi/lo split needed,
//    MFMA count halves (8->4/wave), accuracy improves ~8x vs bf16.
//  - XOR-swizzled hbuf (256B rows, 16B-chunk ^ n): perfect bank spread for
//    b128 B-frag reads; kills R9's ~160 cyc/step of bank conflicts (5.29M).
//  - v_cvt_pkrtz_f16_f32 h packing (1 instr/pair).
//  R10 lesson: anti-phase/2-barrier serializes; keep same-phase + 1 barrier.

#define BB 1024
#define TT 512
#define HH 128
#define TOUT 516
#define BM 16          // batch rows per block
#define XSTR 513       // xs stride (dwords)
#define YSTR 517       // ybuf stride (dwords)
#define PQS 36         // pq row stride (dwords)

typedef __attribute__((ext_vector_type(8))) _Float16 f16x8;
typedef __attribute__((ext_vector_type(2))) _Float16 f16x2;
typedef __attribute__((ext_vector_type(4))) float f32x4;

#define MFMA16(A_, B_, C_) __builtin_amdgcn_mfma_f32_16x16x32_f16(A_, B_, C_, 0, 0, 0)

__global__ void detect_dtype(const void* w, int* flag) {
    const int lane = threadIdx.x;  // 64 threads
    const __hip_bfloat16* p = (const __hip_bfloat16*)w;
    const float v0 = __bfloat162float(p[lane]);
    const float v1 = __bfloat162float(p[64 + lane]);
    const bool bad = !(fabsf(v0) < 100.0f) || !(fabsf(v1) < 100.0f);
    const unsigned long long m = __ballot(bad);
    if (lane == 0) *flag = (__popcll(m) > 4) ? 1 : 0;  // 1 => data is fp32
}

template <bool F32>
__device__ __forceinline__ float ldg(const void* p, int idx) {
    if (F32) return ((const float*)p)[idx];
    return __bfloat162float(((const __hip_bfloat16*)p)[idx]);
}

// sum of pq row [0..31] (16B-aligned)
__device__ __forceinline__ float red32(const float* pqrow) {
    const f32x4* v = (const f32x4*)pqrow;
    const f32x4 s = ((v[0] + v[1]) + (v[2] + v[3])) + ((v[4] + v[5]) + (v[6] + v[7]));
    return (s[0] + s[1]) + (s[2] + s[3]);
}

// One RNN step. T_: timestep; CUR_: h read buffer; WRITEY_: wave7 dec tile
// emits y[T_-1]; DOPQ_: lanes write decoder partials to pq (tail);
// READX_: prefetch xs[T_+1]; TAILX_: xv from pq reduce (feedback).
// hbuf swizzle: logical 16B-chunk c of row n lives at physical chunk (c^n)&15.
#define STEP(T_, CUR_, WRITEY_, DOPQ_, READX_, TAILX_) do {                     \
    f16x8 bfrag[4];                                                             \
    _Pragma("unroll")                                                           \
    for (int kf = 0; kf < 4; ++kf)                                              \
        bfrag[kf] = *(const f16x8*)&hbuf[CUR_][n][((((kf << 2) | q) ^ n) & 15) << 3]; \
    float xnext = 0.0f;                                                         \
    if (READX_) xnext = xs[n][(T_) + 1];                                        \
    float xv;                                                                   \
    if (TAILX_) xv = red32(&pq[((T_) - 1) & 1][n][0]) + dbv;                    \
    else        xv = xpref;                                                     \
    f32x4 acc0, acc1;                                                           \
    _Pragma("unroll")                                                           \
    for (int r = 0; r < 4; ++r) acc0[r] = fmaf(xv, w0v[r], bsum[r]);            \
    acc1 = (f32x4){0.f, 0.f, 0.f, 0.f};                                         \
    acc0 = MFMA16(wa[0], bfrag[0], acc0);                                       \
    acc1 = MFMA16(wa[1], bfrag[1], acc1);                                       \
    acc0 = MFMA16(wa[2], bfrag[2], acc0);                                       \
    acc1 = MFMA16(wa[3], bfrag[3], acc1);                                       \
    if (isw7 && (WRITEY_)) {  /* dec tile: y[T_-1] = dec . h_old */             \
        f32x4 aD0 = (f32x4){0.f, 0.f, 0.f, 0.f};                                \
        f32x4 aD1 = (f32x4){0.f, 0.f, 0.f, 0.f};                                \
        aD0 = MFMA16(wa_d[0], bfrag[0], aD0);                                   \
        aD1 = MFMA16(wa_d[1], bfrag[1], aD1);                                   \
        aD0 = MFMA16(wa_d[2], bfrag[2], aD0);                                   \
        aD1 = MFMA16(wa_d[3], bfrag[3], aD1);                                   \
        const float yp = aD0[0] + aD1[0] + dbv;                                 \
        if (q == 0) ybuf[n][(T_) - 1] = yp;                                     \
    }                                                                           \
    float p = 0.0f;                                                             \
    float hv[4];                                                                \
    _Pragma("unroll")                                                           \
    for (int r = 0; r < 4; ++r) {                                               \
        const float z = acc0[r] + acc1[r];                                      \
        const float e = __expf(z + z);                                          \
        const float h = fmaf(-2.0f, __builtin_amdgcn_rcpf(e + 1.0f), 1.0f);     \
        if (DOPQ_) p = fmaf(decv[r], h, p);                                     \
        hv[r] = h;                                                              \
    }                                                                           \
    uint2 pk;                                                                   \
    pk.x = __builtin_bit_cast(unsigned, __builtin_amdgcn_cvt_pkrtz(hv[0], hv[1])); \
    pk.y = __builtin_bit_cast(unsigned, __builtin_amdgcn_cvt_pkrtz(hv[2], hv[3])); \
    *(uint2*)&hbuf[(CUR_) ^ 1][n][((((2 * wv + (q >> 1)) ^ n) & 15) << 3) + ((q & 1) << 2)] = pk; \
    if (DOPQ_) pq[(T_) & 1][n][wv * 4 + q] = p;                                 \
    if (READX_) xpref = xnext;                                                  \
    __syncthreads();                                                            \
} while (0)

template <bool F32>
__device__ void rnn_body(const void* __restrict__ xg, const void* __restrict__ h0,
                         const void* __restrict__ w0, const void* __restrict__ b0,
                         const void* __restrict__ W,  const void* __restrict__ bw,
                         const void* __restrict__ dw, const void* __restrict__ db,
                         void* __restrict__ out,
                         float (*xs)[XSTR], float (*ybuf)[YSTR],
                         _Float16 (*hbuf)[BM][HH], float (*pq)[BM][PQS])
{
    const int tid  = threadIdx.x;
    const int lane = tid & 63;
    const int wv   = tid >> 6;        // 0..7 (= m-tile index)
    const int q    = lane >> 4;       // 0..3
    const int n    = lane & 15;       // batch col / A-row-in-tile
    const int row0 = blockIdx.x * BM;
    const bool isw7 = (wv == 7);      // wave-uniform

    // stage x (fp32 in LDS)
    for (int idx = tid; idx < BM * TT; idx += 512) {
        const int rr = idx >> 9, t2 = idx & (TT - 1);
        xs[rr][t2] = ldg<F32>(xg, (row0 + rr) * TT + t2);
    }
    // stage h0 as fp16 (swizzled: chunk c of row rr -> (c^rr)&15)
    for (int idx = tid; idx < BM * HH; idx += 512) {
        const int rr = idx >> 7, ii = idx & (HH - 1);
        const int po = ((((ii >> 3) ^ rr) & 15) << 3) + (ii & 7);
        hbuf[0][rr][po] = (_Float16)ldg<F32>(h0, (row0 + rr) * HH + ii);
    }

    // preload W fragments (A-operand: A[m=lane&15][k=q*8+j]) as fp16
    f16x8 wa[4];
    {
        const int ia = wv * 16 + n;   // W row (output unit)
        #pragma unroll
        for (int kf = 0; kf < 4; ++kf) {
            const int kb = kf * 32 + q * 8;
            f16x8 fr;
            #pragma unroll
            for (int j = 0; j < 8; ++j) fr[j] = (_Float16)ldg<F32>(W, ia * HH + kb + j);
            wa[kf] = fr;
        }
    }
    // dec tile (wave 7): A row 0 = dec_w, rows 1..15 = 0
    f16x8 wa_d[4] = {};
    if (isw7) {
        #pragma unroll
        for (int kf = 0; kf < 4; ++kf) {
            const int kb = kf * 32 + q * 8;
            f16x8 fr = {};
            if (n == 0) {
                #pragma unroll
                for (int j = 0; j < 8; ++j) fr[j] = (_Float16)ldg<F32>(dw, kb + j);
            }
            wa_d[kf] = fr;
        }
    }
    // epilogue constants (C-layout rows: i = wv*16 + q*4 + r)
    float bsum[4], w0v[4], decv[4];
    #pragma unroll
    for (int r = 0; r < 4; ++r) {
        const int ic = wv * 16 + q * 4 + r;
        bsum[r] = ldg<F32>(b0, ic) + ldg<F32>(bw, ic);
        w0v[r]  = ldg<F32>(w0, ic);
        decv[r] = ldg<F32>(dw, ic);
    }
    const float dbv = ldg<F32>(db, 0);

    __syncthreads();

    float xpref = xs[n][0];

    // t = 0: no y yet, no pq
    STEP(0, 0, false, false, true, false);

    // main: t = 1..510, compile-time cur (odd reads buf1, even reads buf0)
    #pragma unroll 1
    for (int t = 1; t < 511; t += 2) {
        STEP(t,     1, true, false, true, false);
        STEP(t + 1, 0, true, false, true, false);
    }

    // t = 511: last x step; start pq for tail feedback
    STEP(511, 1, true, true, false, false);

    // tail: t = 512..515, xv = y[t-1] via pq reduce
    #pragma unroll 1
    for (int t = 512; t < 516; ++t) {
        STEP(t, t & 1, true, true, false, true);
    }

    // final y[515]
    if (isw7 && q == 0)
        ybuf[n][TOUT - 1] = red32(&pq[(TOUT - 1) & 1][n][0]) + dbv;
    __syncthreads();

    // flush outputs (coalesced over t)
    for (int rr = 0; rr < BM; ++rr)
        for (int t2 = tid; t2 < TOUT; t2 += 512) {
            const int o = (row0 + rr) * TOUT + t2;
            const float y = ybuf[rr][t2];
            if (F32) ((float*)out)[o] = y;
            else     ((__hip_bfloat16*)out)[o] = __float2bfloat16(y);
        }
}

__global__ __launch_bounds__(512, 2)
void rnn_mfma(const void* __restrict__ xg, const void* __restrict__ h0,
              const void* __restrict__ w0, const void* __restrict__ b0,
              const void* __restrict__ W,  const void* __restrict__ bw,
              const void* __restrict__ dw, const void* __restrict__ db,
              void* __restrict__ out, const int* __restrict__ flag)
{
    __shared__ float xs[BM][XSTR];                          // 32.8 KB
    __shared__ float ybuf[BM][YSTR];                        // 33.1 KB
    __shared__ __align__(16) _Float16 hbuf[2][BM][HH];      // 8 KB
    __shared__ __align__(16) float pq[2][BM][PQS];          // 4.6 KB

    const int f = *(volatile const int*)flag;  // block-uniform
    if (f) rnn_body<true >(xg, h0, w0, b0, W, bw, dw, db, out, xs, ybuf, hbuf, pq);
    else   rnn_body<false>(xg, h0, w0, b0, W, bw, dw, db, out, xs, ybuf, hbuf, pq);
}

extern "C" void kernel_launch(void* const* d_in, const int* in_sizes, int n_in,
                              void* d_out, int out_size, void* d_ws, size_t ws_size,
                              hipStream_t stream) {
    int* flag = (int*)d_ws;
    detect_dtype<<<1, 64, 0, stream>>>(d_in[4], flag);  // probe fc_w
    rnn_mfma<<<BB / BM, 512, 0, stream>>>(d_in[0], d_in[1], d_in[2], d_in[3],
                                          d_in[4], d_in[5], d_in[6], d_in[7],
                                          d_out, flag);
}